// Round 1
// baseline (389.303 us; speedup 1.0000x reference)
//
#include <hip/hip_runtime.h>

typedef __bf16 bf16_t;
typedef __bf16 bf16x8 __attribute__((ext_vector_type(8)));
typedef float f32x4 __attribute__((ext_vector_type(4)));

#define GM 16384   // rows of x / out
#define GN 2048    // D_OUT
#define GK 2048    // D_IN

// -------- fp32 -> bf16 convert (8 elems/thread, float4 in, 16B out) --------
__global__ __launch_bounds__(256) void f32_to_bf16(const float* __restrict__ s,
                                                   bf16_t* __restrict__ d) {
    long i = ((long)blockIdx.x * 256 + threadIdx.x) * 8;
    float4 v0 = *(const float4*)(s + i);
    float4 v1 = *(const float4*)(s + i + 4);
    bf16x8 o;
    o[0] = (bf16_t)v0.x; o[1] = (bf16_t)v0.y; o[2] = (bf16_t)v0.z; o[3] = (bf16_t)v0.w;
    o[4] = (bf16_t)v1.x; o[5] = (bf16_t)v1.y; o[6] = (bf16_t)v1.z; o[7] = (bf16_t)v1.w;
    *(bf16x8*)(d + i) = o;
}

// -------- async global->LDS, 16B per lane (m97 pattern) --------
__device__ __forceinline__ void async16(const void* g, void* l) {
    __builtin_amdgcn_global_load_lds(
        (__attribute__((address_space(1))) void*)g,
        (__attribute__((address_space(3))) void*)l,
        16, 0, 0);
}

// -------- GEMM: C[M][N] = A[M][K] * B[N][K]^T * scale + 0.1*bias[N] --------
// 128x128 tile, BK=32, 256 threads = 4 waves in 2x2, each wave 64x64
// (4x4 grid of 16x16x32 bf16 MFMAs). m97 2-barrier K-loop structure.
__global__ __launch_bounds__(256, 2) void gemm_bf16_bt(
    const bf16_t* __restrict__ A,
    const bf16_t* __restrict__ B,
    const float* __restrict__ bias,
    float* __restrict__ C) {
    // No inner-dim padding: global_load_lds requires LDS dst = wave base + lane*16
    __shared__ bf16_t As[128 * 32];
    __shared__ bf16_t Bs[128 * 32];

    const int t    = threadIdx.x;
    const int bm0  = blockIdx.y * 128;
    const int bn0  = blockIdx.x * 128;

    const int wave = t >> 6;
    const int lane = t & 63;
    const int wm   = (wave >> 1) * 64;
    const int wn   = (wave & 1) * 64;
    const int fr   = lane & 15;        // frag row (m or n)
    const int fk   = (lane >> 4) * 8;  // frag k offset (quad*8)

    // Staging map: thread t covers 8 contiguous K-elements.
    // Issue 0 -> tile rows 0..63, issue 1 -> rows 64..127.
    const int srow = t >> 2;          // 0..63
    const int scol = (t & 3) * 8;     // 0,8,16,24
    const bf16_t* gA = A + (bm0 + srow) * GK + scol;
    const bf16_t* gB = B + (bn0 + srow) * GK + scol;
    bf16_t* lA = &As[t * 8];          // == (srow*32 + scol), lane-contiguous 16B
    bf16_t* lB = &Bs[t * 8];

    f32x4 acc[4][4] = {};

    for (int k0 = 0; k0 < GK; k0 += 32) {
        async16(gA + k0,             lA);
        async16(gA + k0 + 64 * GK,   lA + 64 * 32);
        async16(gB + k0,             lB);
        async16(gB + k0 + 64 * GK,   lB + 64 * 32);
        __syncthreads();   // compiler emits vmcnt(0) drain -> tiles visible

        bf16x8 af[4], bf[4];
#pragma unroll
        for (int i = 0; i < 4; ++i)
            af[i] = *(const bf16x8*)&As[(wm + i * 16 + fr) * 32 + fk];
#pragma unroll
        for (int i = 0; i < 4; ++i)
            bf[i] = *(const bf16x8*)&Bs[(wn + i * 16 + fr) * 32 + fk];

#pragma unroll
        for (int mi = 0; mi < 4; ++mi)
#pragma unroll
            for (int ni = 0; ni < 4; ++ni)
                acc[mi][ni] = __builtin_amdgcn_mfma_f32_16x16x32_bf16(
                    af[mi], bf[ni], acc[mi][ni], 0, 0, 0);
        __syncthreads();   // protect LDS before next overwrite
    }

    // Epilogue: C/D layout col=lane&15, row=(lane>>4)*4+reg  [m89-verified]
    const float scale = 0.022097086912079608f;  // 1/sqrt(2048)
    const int crow0 = bm0 + wm + ((lane >> 4) << 2);
    const int ccol0 = bn0 + wn + fr;
#pragma unroll
    for (int ni = 0; ni < 4; ++ni) {
        const int col = ccol0 + ni * 16;
        const float bv = 0.1f * bias[col];
#pragma unroll
        for (int mi = 0; mi < 4; ++mi) {
            const int row = crow0 + mi * 16;
#pragma unroll
            for (int r = 0; r < 4; ++r)
                C[(row + r) * GN + col] = acc[mi][ni][r] * scale + bv;
        }
    }
}

extern "C" void kernel_launch(void* const* d_in, const int* in_sizes, int n_in,
                              void* d_out, int out_size, void* d_ws, size_t ws_size,
                              hipStream_t stream) {
    const float* x = (const float*)d_in[0];   // [16384, 2048]
    const float* w = (const float*)d_in[1];   // [2048, 2048]
    const float* b = (const float*)d_in[2];   // [1, 2048]
    float* out = (float*)d_out;               // [16384, 2048]

    bf16_t* xb = (bf16_t*)d_ws;                   // 64 MiB
    bf16_t* wb = xb + (size_t)GM * GK;            // + 8 MiB  (ws needs ~75.5 MB)

    f32_to_bf16<<<(GM * GK) / (8 * 256), 256, 0, stream>>>(x, xb);
    f32_to_bf16<<<(GN * GK) / (8 * 256), 256, 0, stream>>>(w, wb);

    dim3 grid(GN / 128, GM / 128);   // (16, 128) = 2048 blocks
    gemm_bf16_bt<<<grid, 256, 0, stream>>>(xb, wb, b, out);
}

// Round 3
// 352.043 us; speedup vs baseline: 1.1058x; 1.1058x over previous
//
#include <hip/hip_runtime.h>

typedef __bf16 bf16_t;
typedef __bf16 bf16x8 __attribute__((ext_vector_type(8)));
typedef float f32x4 __attribute__((ext_vector_type(4)));

#define GM 16384   // rows of x / out
#define GN 2048    // D_OUT
#define GK 2048    // D_IN
#define NX (GM * GK)   // 33554432 x elements
#define NW (GN * GK)   // 4194304 w elements

// -------- merged fp32 -> bf16 convert (8 elems/thread, nt loads) --------
__global__ __launch_bounds__(256) void cvt_all(const float* __restrict__ x,
                                               const float* __restrict__ w,
                                               bf16_t* __restrict__ xb,
                                               bf16_t* __restrict__ wb) {
    long i = ((long)blockIdx.x * 256 + threadIdx.x) * 8;
    const float* s;
    bf16_t* d;
    if (i < NX) { s = x + i; d = xb + i; }          // wave-uniform branch
    else        { s = w + (i - NX); d = wb + (i - NX); }
    f32x4 v0 = __builtin_nontemporal_load((const f32x4*)s);      // single-use fp32
    f32x4 v1 = __builtin_nontemporal_load((const f32x4*)(s + 4));
    bf16x8 o;
    o[0] = (bf16_t)v0.x; o[1] = (bf16_t)v0.y; o[2] = (bf16_t)v0.z; o[3] = (bf16_t)v0.w;
    o[4] = (bf16_t)v1.x; o[5] = (bf16_t)v1.y; o[6] = (bf16_t)v1.z; o[7] = (bf16_t)v1.w;
    *(bf16x8*)d = o;   // bf16 stays cacheable — GEMM re-reads it
}

// -------- async global->LDS, 16B per lane --------
__device__ __forceinline__ void async16(const void* g, void* l) {
    __builtin_amdgcn_global_load_lds(
        (__attribute__((address_space(1))) void*)g,
        (__attribute__((address_space(3))) void*)l,
        16, 0, 0);
}

// -------- GEMM: C = A * B^T * scale + 0.1*bias --------
// 128x128 tile, BK=64 (32 MFMA per barrier pair), XOR-swizzled LDS:
// 16B chunk (row, g) of a tile lives at position (row, g ^ (row&7)).
// Staging permutes the GLOBAL fetch per lane (free — same 128B row segment),
// keeping the LDS-contiguous destination global_load_lds requires.
__global__ __launch_bounds__(256, 2) void gemm_bf16_bt(
    const bf16_t* __restrict__ A,
    const bf16_t* __restrict__ B,
    const float* __restrict__ bias,
    float* __restrict__ C) {
    __shared__ bf16_t As[128 * 64];   // 16 KB
    __shared__ bf16_t Bs[128 * 64];   // 16 KB

    const int t    = threadIdx.x;
    const int bm0  = blockIdx.y * 128;
    const int bn0  = blockIdx.x * 128;

    const int wave = t >> 6;
    const int lane = t & 63;
    const int wm   = (wave >> 1) * 64;
    const int wn   = (wave & 1) * 64;
    const int fr   = lane & 15;       // frag row (m or n) == C col
    const int quad = lane >> 4;

    // Staging: issue i covers tile rows [i*32, i*32+32). Thread t is LDS
    // chunk position p = i*256 + t -> row = i*32 + (t>>3), stored-g = t&7,
    // fetches global col-group (t&7) ^ (row&7)  (row&7 == (t>>3)&7).
    const int srow = t >> 3;                         // 0..31
    const int scol = (((t & 7) ^ (srow & 7)) * 8);   // swizzled col, elems
    const bf16_t* gA0 = A + (size_t)(bm0 + srow) * GK + scol;
    const bf16_t* gB0 = B + (size_t)(bn0 + srow) * GK + scol;

    // Frag read chunk offsets: row R has R&7 == fr&7 (wm, i*16 are mult of 8)
    const int sz  = fr & 7;
    const int ch0 = ((quad)     ^ sz) * 8;   // k-half 0: chunks 0..3
    const int ch1 = ((4 + quad) ^ sz) * 8;   // k-half 1: chunks 4..7

    f32x4 acc[4][4] = {};

    for (int k0 = 0; k0 < GK; k0 += 64) {
#pragma unroll
        for (int i = 0; i < 4; ++i) {
            async16(gA0 + (size_t)i * 32 * GK + k0, &As[(i * 256 + t) * 8]);
            async16(gB0 + (size_t)i * 32 * GK + k0, &Bs[(i * 256 + t) * 8]);
        }
        __syncthreads();

        bf16x8 af[4], bf[4];
        // ---- k-half 0 ----
#pragma unroll
        for (int i = 0; i < 4; ++i)
            af[i] = *(const bf16x8*)&As[(wm + i * 16 + fr) * 64 + ch0];
#pragma unroll
        for (int i = 0; i < 4; ++i)
            bf[i] = *(const bf16x8*)&Bs[(wn + i * 16 + fr) * 64 + ch0];
#pragma unroll
        for (int mi = 0; mi < 4; ++mi)
#pragma unroll
            for (int ni = 0; ni < 4; ++ni)
                acc[mi][ni] = __builtin_amdgcn_mfma_f32_16x16x32_bf16(
                    af[mi], bf[ni], acc[mi][ni], 0, 0, 0);
        // ---- k-half 1 ----
#pragma unroll
        for (int i = 0; i < 4; ++i)
            af[i] = *(const bf16x8*)&As[(wm + i * 16 + fr) * 64 + ch1];
#pragma unroll
        for (int i = 0; i < 4; ++i)
            bf[i] = *(const bf16x8*)&Bs[(wn + i * 16 + fr) * 64 + ch1];
#pragma unroll
        for (int mi = 0; mi < 4; ++mi)
#pragma unroll
            for (int ni = 0; ni < 4; ++ni)
                acc[mi][ni] = __builtin_amdgcn_mfma_f32_16x16x32_bf16(
                    af[mi], bf[ni], acc[mi][ni], 0, 0, 0);
        __syncthreads();
    }

    // Epilogue: C/D layout col=lane&15, row=quad*4+reg [m89-verified].
    // Nontemporal stores: C is single-use, keep A/B resident in L2/L3.
    const float scale = 0.022097086912079608f;  // 1/sqrt(2048)
    const int crow0 = bm0 + wm + (quad << 2);
    const int ccol0 = bn0 + wn + fr;
#pragma unroll
    for (int ni = 0; ni < 4; ++ni) {
        const int col = ccol0 + ni * 16;
        const float bv = 0.1f * bias[col];
#pragma unroll
        for (int mi = 0; mi < 4; ++mi) {
            const int row = crow0 + mi * 16;
#pragma unroll
            for (int r = 0; r < 4; ++r)
                __builtin_nontemporal_store(acc[mi][ni][r] * scale + bv,
                                            &C[(size_t)(row + r) * GN + col]);
        }
    }
}

extern "C" void kernel_launch(void* const* d_in, const int* in_sizes, int n_in,
                              void* d_out, int out_size, void* d_ws, size_t ws_size,
                              hipStream_t stream) {
    const float* x = (const float*)d_in[0];   // [16384, 2048]
    const float* w = (const float*)d_in[1];   // [2048, 2048]
    const float* b = (const float*)d_in[2];   // [1, 2048]
    float* out = (float*)d_out;               // [16384, 2048]

    bf16_t* xb = (bf16_t*)d_ws;                   // 64 MiB
    bf16_t* wb = xb + (size_t)NX;                 // + 8 MiB

    cvt_all<<<(NX + NW) / (8 * 256), 256, 0, stream>>>(x, w, xb, wb);

    dim3 grid(GN / 128, GM / 128);   // (16, 128) = 2048 blocks
    gemm_bf16_bt<<<grid, 256, 0, stream>>>(xb, wb, b, out);
}